// Round 4
// baseline (354.523 us; speedup 1.0000x reference)
//
#include <hip/hip_runtime.h>

#define DMODEL 512
#define KPAD   256
#define EPS_IN 1e-4f
#define EPS_LN 1e-5f
#define CLIPV  5.0f

typedef float f32x4 __attribute__((ext_vector_type(4)));
typedef short s16x8 __attribute__((ext_vector_type(8)));

__device__ __forceinline__ unsigned short f2bf(float f) {
    union { float f; unsigned u; } v; v.f = f;
    unsigned r = v.u + 0x7fffu + ((v.u >> 16) & 1u);
    return (unsigned short)(r >> 16);
}

// Combined weight: Wtc[col][k], k in unified 256-slot space.
// k 0..63 -> W0, 64..191 -> W1, 192..239 -> W2, 240..242 -> biases, else 0.
__global__ __launch_bounds__(256) void build_wt(
    const float* __restrict__ W0, const float* __restrict__ W1, const float* __restrict__ W2,
    const float* __restrict__ b0, const float* __restrict__ b1, const float* __restrict__ b2,
    unsigned short* __restrict__ Wt)
{
    const int idx = blockIdx.x * 256 + threadIdx.x;   // 512*256 total
    const int col = idx >> 8, k = idx & 255;
    float w;
    if      (k <  64) w = W0[(size_t)k * DMODEL + col];
    else if (k < 192) w = W1[(size_t)(k - 64) * DMODEL + col];
    else if (k < 240) w = W2[(size_t)(k - 192) * DMODEL + col];
    else if (k == 240) w = b0[col];
    else if (k == 241) w = b1[col];
    else if (k == 242) w = b2[col];
    else w = 0.0f;
    Wt[idx] = f2bf(w);
}

struct EmbedArgs {
    const float *x0, *x1, *x2;
    const float *mean0, *mean1, *mean2;
    const float *var0, *var1, *var2;
    const float *g0, *g1, *g2, *e0, *e1, *e2;
    const unsigned short* Wt;
    const int* index_map;
    const int* batch_index;
    float* out; float* out_t; float* out_e;
    int n0, n01, total;
};

// Block: 64 OUTPUT rows x 512 cols. 8 waves = 2(M) x 4(N). Wave: 32 rows x 128 cols.
// Writes are linear; input rows gathered via index_map.
__global__ __launch_bounds__(512, 4) void embed_all(EmbedArgs a)
{
    __shared__ char lds[64 * KPAD * 2 + 64 * 4 * sizeof(float2) + 64 * sizeof(int)];
    float2* red = reinterpret_cast<float2*>(lds + 64 * KPAD * 2);
    int*   ityp = reinterpret_cast<int*>(lds + 64 * KPAD * 2 + 64 * 4 * sizeof(float2));

    const int tid  = threadIdx.x;
    const int lane = tid & 63;
    const int w    = tid >> 6;     // 0..7
    const int wm   = w >> 2;       // 0..1
    const int wn   = w & 3;        // 0..3
    const int l15  = lane & 15;
    const int g    = lane >> 4;    // 0..3
    const int row0 = blockIdx.x * 64;

    // ---- stage: gather rows, InputNorm -> bf16 LDS tile [64][256], XOR swizzle
#pragma unroll
    for (int it = 0; it < 4; ++it) {
        const int idx = tid + it * 512;        // 64 rows x 32 segs
        const int r = idx >> 5, s = idx & 31;
        const int j = row0 + r;
        s16x8 pk;
#pragma unroll
        for (int jj = 0; jj < 8; ++jj) pk[jj] = 0;

        if (j < a.total) {
            const int rg = a.index_map[j];
            const float* xp; const float* mn; const float* vr;
            int t, koff, F, rl;
            if (rg < a.n0)       { t = 0; xp = a.x0; mn = a.mean0; vr = a.var0; koff = 0;   F = 64;  rl = rg; }
            else if (rg < a.n01) { t = 1; xp = a.x1; mn = a.mean1; vr = a.var1; koff = 64;  F = 128; rl = rg - a.n0; }
            else                 { t = 2; xp = a.x2; mn = a.mean2; vr = a.var2; koff = 192; F = 48;  rl = rg - a.n01; }

            const int k0 = s * 8;
            if (k0 >= koff && k0 < koff + F) {
                const int c = k0 - koff;
                const float4 xv0 = *(const float4*)(xp + (size_t)rl * F + c);
                const float4 xv1 = *(const float4*)(xp + (size_t)rl * F + c + 4);
                const float4 m0 = *(const float4*)(mn + c);
                const float4 m1 = *(const float4*)(mn + c + 4);
                const float4 v0 = *(const float4*)(vr + c);
                const float4 v1 = *(const float4*)(vr + c + 4);
                const float tv[8] = {xv0.x - m0.x, xv0.y - m0.y, xv0.z - m0.z, xv0.w - m0.w,
                                     xv1.x - m1.x, xv1.y - m1.y, xv1.z - m1.z, xv1.w - m1.w};
                const float iv[8] = {rsqrtf(v0.x + EPS_IN), rsqrtf(v0.y + EPS_IN),
                                     rsqrtf(v0.z + EPS_IN), rsqrtf(v0.w + EPS_IN),
                                     rsqrtf(v1.x + EPS_IN), rsqrtf(v1.y + EPS_IN),
                                     rsqrtf(v1.z + EPS_IN), rsqrtf(v1.w + EPS_IN)};
#pragma unroll
                for (int jj = 0; jj < 8; ++jj)
                    pk[jj] = (short)f2bf(fminf(fmaxf(tv[jj] * iv[jj], -CLIPV), CLIPV));
            } else if (s == 30) {
                pk[t] = (short)f2bf(1.0f);     // bias slot k = 240 + t
            }
            if (s == 0) {
                ityp[r] = t;
                a.out_t[j] = (float)a.batch_index[rg];
                a.out_e[j] = (float)t;
            }
        } else if (s == 0) {
            ityp[r] = 0;
        }
        int byte = r * (KPAD * 2) + s * 16;
        byte ^= (r & 7) << 4;
        *reinterpret_cast<s16x8*>(lds + byte) = pk;
    }
    __syncthreads();

    // ---- MFMA: K=256 unified; acc[m][t] 16x16 tiles
    f32x4 acc[2][8];
#pragma unroll
    for (int m = 0; m < 2; ++m)
#pragma unroll
        for (int t = 0; t < 8; ++t) acc[m][t] = (f32x4)0.0f;

    const int arow = wm * 32 + l15;
    const unsigned short* wtl = a.Wt + (size_t)(wn * 128 + l15) * KPAD + g * 8;

#pragma unroll
    for (int ks = 0; ks < KPAD / 32; ++ks) {
        int a0b = arow * (KPAD * 2) + ks * 64 + g * 16;        a0b ^= (arow & 7) << 4;
        int a1b = (arow + 16) * (KPAD * 2) + ks * 64 + g * 16; a1b ^= (arow & 7) << 4;
        const s16x8 a0 = *reinterpret_cast<const s16x8*>(lds + a0b);
        const s16x8 a1 = *reinterpret_cast<const s16x8*>(lds + a1b);
#pragma unroll
        for (int t = 0; t < 8; ++t) {
            const s16x8 bf = *reinterpret_cast<const s16x8*>(wtl + (size_t)t * 16 * KPAD + ks * 32);
            acc[0][t] = __builtin_amdgcn_mfma_f32_16x16x32_bf16(a0, bf, acc[0][t], 0, 0, 0);
            acc[1][t] = __builtin_amdgcn_mfma_f32_16x16x32_bf16(a1, bf, acc[1][t], 0, 0, 0);
        }
    }

    // ---- LayerNorm partials (bias already in acc via k-slots)
    {
        float ps[2][4] = {{0}}, pq[2][4] = {{0}};
#pragma unroll
        for (int m = 0; m < 2; ++m)
#pragma unroll
            for (int t = 0; t < 8; ++t)
#pragma unroll
                for (int jj = 0; jj < 4; ++jj) {
                    const float v = fmaxf(acc[m][t][jj], 0.0f);
                    ps[m][jj] += v;
                    pq[m][jj] = fmaf(v, v, pq[m][jj]);
                }
#pragma unroll
        for (int off = 1; off < 16; off <<= 1)
#pragma unroll
            for (int m = 0; m < 2; ++m)
#pragma unroll
                for (int jj = 0; jj < 4; ++jj) {
                    ps[m][jj] += __shfl_xor(ps[m][jj], off, 64);
                    pq[m][jj] += __shfl_xor(pq[m][jj], off, 64);
                }
        if (l15 == 0) {
#pragma unroll
            for (int m = 0; m < 2; ++m)
#pragma unroll
                for (int jj = 0; jj < 4; ++jj) {
                    const int rl = wm * 32 + m * 16 + 4 * g + jj;
                    red[rl * 4 + wn] = make_float2(ps[m][jj], pq[m][jj]);
                }
        }
    }
    __syncthreads();

    // ---- finish LN + linear store
#pragma unroll
    for (int m = 0; m < 2; ++m)
#pragma unroll
        for (int jj = 0; jj < 4; ++jj) {
            const int rl = wm * 32 + m * 16 + 4 * g + jj;
            const int j = row0 + rl;
            if (j >= a.total) continue;
            float s = 0.0f, q = 0.0f;
#pragma unroll
            for (int wq = 0; wq < 4; ++wq) { const float2 e = red[rl * 4 + wq]; s += e.x; q += e.y; }
            const float mu = s * (1.0f / DMODEL);
            const float vv = fmaxf(q * (1.0f / DMODEL) - mu * mu, 0.0f);
            const float sc = rsqrtf(vv + EPS_LN);
            const int t = ityp[rl];
            const float* gp = (t == 0 ? a.g0 : (t == 1 ? a.g1 : a.g2)) + wn * 128 + l15;
            const float* ep = (t == 0 ? a.e0 : (t == 1 ? a.e1 : a.e2)) + wn * 128 + l15;
            float* op = a.out + (size_t)j * DMODEL + wn * 128 + l15;
#pragma unroll
            for (int tt = 0; tt < 8; ++tt) {
                const float v = fmaxf(acc[m][tt][jj], 0.0f);
                op[tt * 16] = fmaf(gp[tt * 16] * sc, v - mu, ep[tt * 16]);
            }
        }
}

extern "C" void kernel_launch(void* const* d_in, const int* in_sizes, int n_in,
                              void* d_out, int out_size, void* d_ws, size_t ws_size,
                              hipStream_t stream)
{
    const int F0 = 64, F1 = 128, F2 = 48;
    const int n0 = in_sizes[0]  / F0;
    const int n1 = in_sizes[7]  / F1;
    const int n2 = in_sizes[14] / F2;
    const int total = n0 + n1 + n2;

    float* out   = (float*)d_out;
    float* out_t = out + (size_t)total * DMODEL;
    float* out_e = out_t + total;

    unsigned short* Wtc = (unsigned short*)d_ws;   // 512*256 bf16 = 256 KB

    build_wt<<<(DMODEL * KPAD) / 256, 256, 0, stream>>>(
        (const float*)d_in[3], (const float*)d_in[10], (const float*)d_in[17],
        (const float*)d_in[4], (const float*)d_in[11], (const float*)d_in[18],
        Wtc);

    EmbedArgs a;
    a.x0 = (const float*)d_in[0];  a.x1 = (const float*)d_in[7];  a.x2 = (const float*)d_in[14];
    a.mean0 = (const float*)d_in[1];  a.mean1 = (const float*)d_in[8];   a.mean2 = (const float*)d_in[15];
    a.var0  = (const float*)d_in[2];  a.var1  = (const float*)d_in[9];   a.var2  = (const float*)d_in[16];
    a.g0 = (const float*)d_in[5];  a.g1 = (const float*)d_in[12]; a.g2 = (const float*)d_in[19];
    a.e0 = (const float*)d_in[6];  a.e1 = (const float*)d_in[13]; a.e2 = (const float*)d_in[20];
    a.Wt = Wtc;
    a.index_map   = (const int*)d_in[21];
    a.batch_index = (const int*)d_in[22];
    a.out = out; a.out_t = out_t; a.out_e = out_e;
    a.n0 = n0; a.n01 = n0 + n1; a.total = total;

    const int nb = (total + 63) / 64;
    embed_all<<<nb, 512, 0, stream>>>(a);
}

// Round 5
// 161.026 us; speedup vs baseline: 2.2017x; 2.2017x over previous
//
#include <hip/hip_runtime.h>

#define DMODEL 512
#define EPS_IN 1e-4f
#define EPS_LN 1e-5f
#define CLIPV  5.0f

typedef float f32x4 __attribute__((ext_vector_type(4)));
typedef short s16x8 __attribute__((ext_vector_type(8)));

__device__ __forceinline__ unsigned short f2bf(float f) {
    union { float f; unsigned u; } v; v.f = f;
    unsigned r = v.u + 0x7fffu + ((v.u >> 16) & 1u);
    return (unsigned short)(r >> 16);
}

struct TypeParams {
    const float* x;
    const float* ss;                   // scale[F] then shift[F]
    const unsigned short* Wt;          // [512][KP] bf16, zero-padded K
    const float* b; const float* gamma; const float* beta;
    int n;        // rows of this type
    int offset;   // row offset in concat order
    int nb;       // blocks (32 rows each)
};

// Parts: [A] inv + tbatch/etype, [B] W -> Wt bf16 transpose, [C] scale/shift
__global__ __launch_bounds__(256) void setup_all(
    const int* __restrict__ index_map, const int* __restrict__ batch_index,
    int* __restrict__ inv, float* __restrict__ out_t, float* __restrict__ out_e,
    int total, int n0, int n01, int nbA,
    const float* __restrict__ W0, const float* __restrict__ W1, const float* __restrict__ W2,
    unsigned short* __restrict__ Wt0, unsigned short* __restrict__ Wt1, unsigned short* __restrict__ Wt2,
    const float* __restrict__ mean0, const float* __restrict__ var0,
    const float* __restrict__ mean1, const float* __restrict__ var1,
    const float* __restrict__ mean2, const float* __restrict__ var2,
    float* __restrict__ ss0, float* __restrict__ ss1, float* __restrict__ ss2)
{
    const int nbB = (DMODEL * 256) / 256;
    if (blockIdx.x < (unsigned)nbA) {
        const int j = blockIdx.x * 256 + threadIdx.x;
        if (j >= total) return;
        const int r = index_map[j];
        inv[r] = j;
        out_t[j] = (float)batch_index[r];
        out_e[j] = (r < n0) ? 0.0f : ((r < n01) ? 1.0f : 2.0f);
    } else if (blockIdx.x < (unsigned)(nbA + nbB)) {
        int idx = (blockIdx.x - nbA) * 256 + threadIdx.x;
        const float* W; unsigned short* Wt; int K, Kp;
        if (idx < DMODEL * 64)              { W = W0; Wt = Wt0; K = 64;  Kp = 64; }
        else if (idx < DMODEL * (64 + 128)) { idx -= DMODEL * 64;  W = W1; Wt = Wt1; K = 128; Kp = 128; }
        else                                { idx -= DMODEL * 192; W = W2; Wt = Wt2; K = 48;  Kp = 64; }
        const int nn = idx / Kp, k = idx - nn * Kp;
        const float w = (k < K) ? W[(size_t)k * DMODEL + nn] : 0.0f;
        Wt[idx] = f2bf(w);
    } else {
        const int c = threadIdx.x;
        if (c < 64)  { const float s = rsqrtf(var0[c] + EPS_IN); ss0[c] = s; ss0[64 + c]  = -mean0[c] * s; }
        if (c < 128) { const float s = rsqrtf(var1[c] + EPS_IN); ss1[c] = s; ss1[128 + c] = -mean1[c] * s; }
        if (c < 48)  { const float s = rsqrtf(var2[c] + EPS_IN); ss2[c] = s; ss2[48 + c]  = -mean2[c] * s; }
    }
}

// Block: 32 concat rows x 512 cols, 8 waves. Wave tile: 32 rows x 64 cols (wn).
// LDS A layout: fragment-contiguous 16B units: A[(ks*4+g)*32 + row]
//   -> stage writes linear (addr = tid*16), fragment reads linear per quarter-wave.
template<int F, int KP>
__device__ __forceinline__ void embed_body(
    const TypeParams& p, int bid, const int* __restrict__ inv,
    float* __restrict__ out, char* lds)
{
    const int tid  = threadIdx.x;
    const int lane = tid & 63;
    const int wn   = tid >> 6;     // 0..7 (64-col slice)
    const int l15  = lane & 15;
    const int g    = lane >> 4;    // 0..3
    const int row0 = bid * 32;
    const int n    = p.n;
    constexpr int SEG = KP / 8;    // 16B segments per row
    constexpr int NKS = KP / 32;

    float2* red = reinterpret_cast<float2*>(lds + NKS * 2048);  // [32 rows][8 wn]

    // ---- stage: InputNorm(x) -> bf16, fragment-order LDS (linear write)
    if (tid < 32 * SEG) {
        const int r = tid & 31;        // row within tile
        const int s = tid >> 5;        // 16B segment = ks*4+g
        const int gr = row0 + r;
        const int c = s * 8;
        s16x8 pk;
#pragma unroll
        for (int jj = 0; jj < 8; ++jj) pk[jj] = 0;
        if (gr < n && c < F) {
            const float4 x0 = *(const float4*)(p.x + (size_t)gr * F + c);
            const float4 x1 = *(const float4*)(p.x + (size_t)gr * F + c + 4);
            const float4 sc0 = *(const float4*)(p.ss + c);
            const float4 sc1 = *(const float4*)(p.ss + c + 4);
            const float4 sh0 = *(const float4*)(p.ss + F + c);
            const float4 sh1 = *(const float4*)(p.ss + F + c + 4);
            float t[8];
            t[0] = fmaf(x0.x, sc0.x, sh0.x); t[1] = fmaf(x0.y, sc0.y, sh0.y);
            t[2] = fmaf(x0.z, sc0.z, sh0.z); t[3] = fmaf(x0.w, sc0.w, sh0.w);
            t[4] = fmaf(x1.x, sc1.x, sh1.x); t[5] = fmaf(x1.y, sc1.y, sh1.y);
            t[6] = fmaf(x1.z, sc1.z, sh1.z); t[7] = fmaf(x1.w, sc1.w, sh1.w);
#pragma unroll
            for (int jj = 0; jj < 8; ++jj)
                pk[jj] = (short)f2bf(fminf(fmaxf(t[jj], -CLIPV), CLIPV));
        }
        *reinterpret_cast<s16x8*>(lds + tid * 16) = pk;
    }
    __syncthreads();

    // ---- prefetch inv for this thread's 8 epilogue rows (hide behind MFMA)
    int orow[8];
#pragma unroll
    for (int m = 0; m < 2; ++m)
#pragma unroll
        for (int j = 0; j < 4; ++j) {
            const int rg = row0 + m * 16 + 4 * g + j;
            orow[m * 4 + j] = (rg < n) ? inv[p.offset + rg] : -1;
        }

    // ---- MFMA: acc[m][t]; rows m*16+(4g+j), cols wn*64 + t*16 + l15
    f32x4 acc[2][4];
#pragma unroll
    for (int m = 0; m < 2; ++m)
#pragma unroll
        for (int t = 0; t < 4; ++t) acc[m][t] = (f32x4)0.0f;

    const unsigned short* wtl = p.Wt + (size_t)(wn * 64 + l15) * KP + g * 8;

#pragma unroll
    for (int ks = 0; ks < NKS; ++ks) {
        const int ab = ((ks * 4 + g) * 32 + l15) * 16;
        const s16x8 a0 = *reinterpret_cast<const s16x8*>(lds + ab);
        const s16x8 a1 = *reinterpret_cast<const s16x8*>(lds + ab + 256);
#pragma unroll
        for (int t = 0; t < 4; ++t) {
            const s16x8 bf = *reinterpret_cast<const s16x8*>(wtl + (size_t)t * 16 * KP + ks * 32);
            acc[0][t] = __builtin_amdgcn_mfma_f32_16x16x32_bf16(a0, bf, acc[0][t], 0, 0, 0);
            acc[1][t] = __builtin_amdgcn_mfma_f32_16x16x32_bf16(a1, bf, acc[1][t], 0, 0, 0);
        }
    }

    // ---- epilogue: bias+ReLU, LayerNorm partials
    float bv[4], gv[4], ev[4];
#pragma unroll
    for (int t = 0; t < 4; ++t) {
        const int col = wn * 64 + t * 16 + l15;
        bv[t] = p.b[col]; gv[t] = p.gamma[col]; ev[t] = p.beta[col];
    }

    {
        float ps[2][4] = {{0}}, pq[2][4] = {{0}};
#pragma unroll
        for (int m = 0; m < 2; ++m)
#pragma unroll
            for (int t = 0; t < 4; ++t)
#pragma unroll
                for (int j = 0; j < 4; ++j) {
                    const float v = fmaxf(acc[m][t][j] + bv[t], 0.0f);
                    ps[m][j] += v;
                    pq[m][j] = fmaf(v, v, pq[m][j]);
                }
#pragma unroll
        for (int off = 1; off < 16; off <<= 1)
#pragma unroll
            for (int m = 0; m < 2; ++m)
#pragma unroll
                for (int j = 0; j < 4; ++j) {
                    ps[m][j] += __shfl_xor(ps[m][j], off, 64);
                    pq[m][j] += __shfl_xor(pq[m][j], off, 64);
                }
        if (l15 == 0) {
#pragma unroll
            for (int m = 0; m < 2; ++m)
#pragma unroll
                for (int j = 0; j < 4; ++j) {
                    const int rl = m * 16 + 4 * g + j;
                    red[rl * 8 + wn] = make_float2(ps[m][j], pq[m][j]);
                }
        }
    }
    __syncthreads();

    // ---- finish LN + scatter stores
#pragma unroll
    for (int m = 0; m < 2; ++m)
#pragma unroll
        for (int j = 0; j < 4; ++j) {
            const int od = orow[m * 4 + j];
            if (od < 0) continue;
            const int rl = m * 16 + 4 * g + j;
            float s = 0.0f, q = 0.0f;
#pragma unroll
            for (int wq = 0; wq < 8; ++wq) { const float2 e = red[rl * 8 + wq]; s += e.x; q += e.y; }
            const float mu = s * (1.0f / DMODEL);
            const float vv = fmaxf(q * (1.0f / DMODEL) - mu * mu, 0.0f);
            const float sc = rsqrtf(vv + EPS_LN);
            float* op = out + (size_t)od * DMODEL + wn * 64 + l15;
#pragma unroll
            for (int t = 0; t < 4; ++t) {
                const float v = fmaxf(acc[m][t][j] + bv[t], 0.0f);
                op[t * 16] = fmaf(gv[t] * sc, v - mu, ev[t]);
            }
        }
}

__global__ __launch_bounds__(512, 4) void embed_all(
    TypeParams p0, TypeParams p1, TypeParams p2,
    const int* __restrict__ inv, float* __restrict__ out)
{
    extern __shared__ char lds[];
    const int bid = blockIdx.x;
    if (bid < p0.nb)                embed_body<64, 64>  (p0, bid, inv, out, lds);
    else if (bid < p0.nb + p1.nb)   embed_body<128, 128>(p1, bid - p0.nb, inv, out, lds);
    else                            embed_body<48, 64>  (p2, bid - p0.nb - p1.nb, inv, out, lds);
}

extern "C" void kernel_launch(void* const* d_in, const int* in_sizes, int n_in,
                              void* d_out, int out_size, void* d_ws, size_t ws_size,
                              hipStream_t stream)
{
    const int F0 = 64, F1 = 128, F2 = 48;
    const int n0 = in_sizes[0]  / F0;
    const int n1 = in_sizes[7]  / F1;
    const int n2 = in_sizes[14] / F2;
    const int total = n0 + n1 + n2;

    float* out   = (float*)d_out;
    float* out_t = out + (size_t)total * DMODEL;
    float* out_e = out_t + total;

    // ws layout: inv[total] ints | Wt0/Wt1/Wt2 bf16 | ss0/ss1/ss2 f32
    int* inv = (int*)d_ws;
    unsigned short* Wt0 = (unsigned short*)((char*)d_ws + (((size_t)total * 4 + 255) & ~(size_t)255));
    unsigned short* Wt1 = Wt0 + DMODEL * 64;
    unsigned short* Wt2 = Wt1 + DMODEL * 128;
    float* ss0 = (float*)(Wt2 + DMODEL * 64);
    float* ss1 = ss0 + 128;
    float* ss2 = ss1 + 256;

    const int* index_map   = (const int*)d_in[21];
    const int* batch_index = (const int*)d_in[22];

    const int nbA = (total + 255) / 256;
    const int nbB = (DMODEL * 256) / 256;
    setup_all<<<nbA + nbB + 1, 256, 0, stream>>>(
        index_map, batch_index, inv, out_t, out_e, total, n0, n0 + n1, nbA,
        (const float*)d_in[3], (const float*)d_in[10], (const float*)d_in[17],
        Wt0, Wt1, Wt2,
        (const float*)d_in[1],  (const float*)d_in[2],
        (const float*)d_in[8],  (const float*)d_in[9],
        (const float*)d_in[15], (const float*)d_in[16],
        ss0, ss1, ss2);

    TypeParams p0{(const float*)d_in[0],  ss0, Wt0,
                  (const float*)d_in[4],  (const float*)d_in[5],  (const float*)d_in[6],
                  n0, 0,       (n0 + 31) / 32};
    TypeParams p1{(const float*)d_in[7],  ss1, Wt1,
                  (const float*)d_in[11], (const float*)d_in[12], (const float*)d_in[13],
                  n1, n0,      (n1 + 31) / 32};
    TypeParams p2{(const float*)d_in[14], ss2, Wt2,
                  (const float*)d_in[18], (const float*)d_in[19], (const float*)d_in[20],
                  n2, n0 + n1, (n2 + 31) / 32};

    const int nb = p0.nb + p1.nb + p2.nb;
    const int lds_size = 4 * 2048 + 32 * 8 * sizeof(float2);  // max NKS=4: 8KB A + 2KB red
    embed_all<<<nb, 512, lds_size, stream>>>(p0, p1, p2, inv, out);
}